// Round 12
// baseline (152.168 us; speedup 1.0000x reference)
//
#include <hip/hip_runtime.h>

#define L_LEN  1024
#define FDIM   16
#define PERIOD 24
#define HDIM   128
#define BATCH  1024
#define DDIM   (L_LEN*FDIM)      // 16384
#define NH3    (3*HDIM)          // 384
#define THALF  12
#define NCLS   10
#define FH     (FDIM*HDIM)       // 2048
#define NLB    8                 // l-strip per build_wp block

typedef short bf16x8  __attribute__((ext_vector_type(8)));
typedef short bf16x16 __attribute__((ext_vector_type(16)));
typedef float f32x4   __attribute__((ext_vector_type(4)));
typedef unsigned int u32x4 __attribute__((ext_vector_type(4)));

__device__ __forceinline__ unsigned short f2bf(float f) {
    unsigned int u = __float_as_uint(f);
    u += 0x7FFFu + ((u >> 16) & 1u);           // RNE
    return (unsigned short)(u >> 16);
}
__device__ __forceinline__ float cinv(int p) { return (p < 16) ? (1.0f/43.0f) : (1.0f/42.0f); }

// ---------------- kernel B: fused = bias broadcast + per-phase column sums (f32x4) ----------------
__global__ void init_phase(const float* __restrict__ be0, const float* __restrict__ be1,
                           const float* __restrict__ be2, const float* __restrict__ We1,
                           const float* __restrict__ We2, float* __restrict__ fused,
                           float* __restrict__ u) {
    int idx = blockIdx.x * blockDim.x + threadIdx.x;
    if (idx < BATCH * NH3) {
        int j = idx % NH3;
        float b = (j < HDIM) ? be0[j] : (j < 2*HDIM ? be1[j - HDIM] : be2[j - 2*HDIM]);
        fused[idx] = b;
    }
    if (idx < 2 * PERIOD * (FH / 4)) {          // 24576 vector jobs
        int w    = idx / (PERIOD * (FH / 4));
        int rem  = idx % (PERIOD * (FH / 4));
        int p    = rem / (FH / 4);
        int fh4  = rem % (FH / 4);
        const float* W = (w == 0) ? We1 : We2;
        f32x4 s = {0.f, 0.f, 0.f, 0.f};
        for (int l = p; l < L_LEN; l += PERIOD)
            s += *(const f32x4*)&W[(size_t)l * FH + fh4 * 4];
        *(f32x4*)&u[(size_t)w * PERIOD * FH + p * FH + fh4 * 4] = s;
    }
}

// ---------------- kernel C: build W' (bf16) — register-window, spill-free ----------------
__launch_bounds__(256, 3)
__global__ void build_wp(const float* __restrict__ We0, const float* __restrict__ We2,
                         const float* __restrict__ u, unsigned short* __restrict__ Wp) {
    __shared__ unsigned short tile[3][NLB][16][18];   // 13.8 KB
    int f  = threadIdx.x >> 4;
    int hl = threadIdx.x & 15;
    int h  = blockIdx.x * 16 + hl;
    int l0 = blockIdx.y * NLB;
    int fh = f * HDIM + h;
    const float* u1 = u;
    const float* u2 = u + PERIOD * FH;

    float w0[NLB + 25], w2[NLB + 25];
    #pragma unroll
    for (int i = 0; i < NLB + 25; ++i) {
        int j = l0 - THALF + i;
        if (j >= 0 && j < L_LEN) {
            w0[i] = We0[(size_t)j * FH + fh];
            w2[i] = We2[(size_t)j * FH + fh];
        } else { w0[i] = 0.f; w2[i] = 0.f; }
    }

    float Sv1 = 0.f, Sv2 = 0.f;
    #pragma unroll
    for (int p = 0; p < PERIOD; ++p) {
        float ci = cinv(p);
        Sv1 += u1[p * FH + fh] * ci;
        Sv2 += u2[p * FH + fh] * ci;
    }

    float s0 = 0.f, s2 = 0.f;
    #pragma unroll
    for (int i = 0; i < 25; ++i) { s0 += w0[i]; s2 += w2[i]; }

    const float inv25 = 1.0f / 25.0f;
    #pragma unroll
    for (int r = 0; r < NLB; ++r) {
        int l = l0 + r;
        float out0 = s0 * inv25;
        float mav1, mav2;
        if (l >= THALF && l < L_LEN - THALF) {
            int pr = (l + THALF) % PERIOD;
            float cr = cinv(pr);
            mav1 = (Sv1 + u1[pr * FH + fh] * cr) * inv25;
            mav2 = (Sv2 + u2[pr * FH + fh] * cr) * inv25;
        } else {
            mav1 = 0.f; mav2 = 0.f;
            #pragma unroll
            for (int dl = -THALF; dl <= THALF; ++dl) {
                int j = l + dl;
                if (j >= 0 && j < L_LEN) {
                    int p = j % PERIOD;
                    float ci = cinv(p);
                    mav1 += u1[p * FH + fh] * ci;
                    mav2 += u2[p * FH + fh] * ci;
                }
            }
            mav1 *= inv25; mav2 *= inv25;
        }
        int   pl  = l % PERIOD;
        float cl  = cinv(pl);
        float v1l = u1[pl * FH + fh] * cl;
        float v2l = u2[pl * FH + fh] * cl;
        float out1 = v1l - mav1;
        float out2 = w2[r + THALF] - s2 * inv25 - v2l + mav2;

        tile[0][r][hl][f] = f2bf(out0);
        tile[1][r][hl][f] = f2bf(out1);
        tile[2][r][hl][f] = f2bf(out2);

        s0 += w0[r + 25] - w0[r];
        s2 += w2[r + 25] - w2[r];
    }
    __syncthreads();

    {
        int cid = threadIdx.x;
        #pragma unroll
        for (int pass = 0; pass < 2; ++pass, cid += 256) {
            if (cid < 3 * 16 * NLB) {
                int m  = cid / (16 * NLB);
                int rm = cid % (16 * NLB);
                int h2 = rm / NLB;
                int ll = rm % NLB;
                const unsigned int* src = (const unsigned int*)&tile[m][ll][h2][0];
                union { unsigned int d[8]; bf16x16 v; } cvt;
                #pragma unroll
                for (int i = 0; i < 8; ++i) cvt.d[i] = src[i];
                *(bf16x16*)&Wp[(size_t)(m * HDIM + blockIdx.x * 16 + h2) * DDIM
                               + (size_t)(l0 + ll) * FDIM] = cvt.v;
            }
        }
    }
}

// ---------------- kernel D: fused += x(fp32) @ Wp^T — 128x384 block (full-N), 8 waves ----------------
// Cache-traffic-minimal tiling: A read ONCE (67 MB), B read x8 (100 MB) vs ~400 MB before.
// Per step: aload->reg, bstage (DMA), compute (covers latency), astore, __syncthreads.
// No inline asm: compiler-managed waitcnts; barrier drains DMA before buffer flip.
#define BM3  128
#define BN3  384                 // full N extent
#define BK3  64
#define SPL3 32                  // splitK -> 8 x 32 = 256 blocks = 1/CU
#define KSL3 (DDIM / SPL3)       // 512
#define KST3 (KSL3 / BK3)        // 8
#define LDA3 72                  // A LDS stride: 144B == 4 dw mod 32 -> 2-way (free)

__launch_bounds__(512, 2)
__global__ void gemm_big(const float* __restrict__ x, const unsigned short* __restrict__ Wp,
                         float* __restrict__ fused) {
    __shared__ unsigned short As[2][BM3 * LDA3];   // 2 x 18.4 KB
    __shared__ unsigned short Bs[2][BN3 * BK3];    // 2 x 48 KB, linear dest, swizzled content
    int bid = blockIdx.x;
    int m0 = (bid & 7) * BM3;
    int k0 = (bid >> 3) * KSL3;
    int tid = threadIdx.x, lane = tid & 63, wave = tid >> 6;
    int wm = wave >> 2, wn = wave & 3;             // 2m x 4n -> wave tile 64x96

    int arow = tid >> 2, aseg = tid & 3;           // A: 128 rows x 4 segs of 16 f32
    const float* ag = x + (size_t)(m0 + arow) * DDIM + k0 + aseg * 16;
    int brc  = lane >> 3;                          // row within 8-row chunk
    int bsg  = (lane & 7) ^ brc;                   // T2 source-pre-swizzle

    f32x4 Ra[4];
    f32x4 acc[4][6] = {};

    auto aload = [&](int s) {
        const float* a = ag + s * BK3;
        #pragma unroll
        for (int i = 0; i < 4; ++i) Ra[i] = *(const f32x4*)(a + 4 * i);
    };
    auto astore = [&](int buf) {
        unsigned int w[8];
        #pragma unroll
        for (int t = 0; t < 8; ++t) {
            float lo = Ra[t >> 1][(t & 1) * 2];
            float hi = Ra[t >> 1][(t & 1) * 2 + 1];
            asm("v_cvt_pk_bf16_f32 %0, %1, %2" : "=v"(w[t]) : "v"(lo), "v"(hi));
        }
        unsigned short* dst = &As[buf][arow * LDA3 + aseg * 16];
        u32x4 v0 = {w[0], w[1], w[2], w[3]};
        u32x4 v1 = {w[4], w[5], w[6], w[7]};
        *(u32x4*)dst       = v0;
        *(u32x4*)(dst + 8) = v1;
    };
    auto bstage = [&](int buf, int s) {
        #pragma unroll
        for (int q = 0; q < 6; ++q) {
            int c = wave * 6 + q;                  // 8-row chunk id (0..47) -> 384 rows
            const unsigned short* g = Wp + (size_t)(c * 8 + brc) * DDIM
                                        + k0 + s * BK3 + bsg * 8;
            __builtin_amdgcn_global_load_lds(
                (const __attribute__((address_space(1))) void*)g,
                (__attribute__((address_space(3))) void*)(&Bs[buf][c * 512]), 16, 0, 0);
        }
    };
    int frow = lane & 15, hi4 = lane >> 4;
    auto compute = [&](int buf) {
        #pragma unroll
        for (int ks = 0; ks < 2; ++ks) {
            bf16x8 av[4], bv[6];
            #pragma unroll
            for (int i = 0; i < 4; ++i)
                av[i] = *(const bf16x8*)&As[buf][(wm*64 + i*16 + frow) * LDA3 + ks*32 + hi4*8];
            #pragma unroll
            for (int j = 0; j < 6; ++j) {
                int rB = wn*96 + j*16 + frow;
                int sL = (ks*4 + hi4) ^ (frow & 7);    // un-swizzle on read
                bv[j] = *(const bf16x8*)&Bs[buf][rB * BK3 + sL * 8];
            }
            #pragma unroll
            for (int i = 0; i < 4; ++i)
                #pragma unroll
                for (int j = 0; j < 6; ++j)
                    acc[i][j] = __builtin_amdgcn_mfma_f32_16x16x32_bf16(av[i], bv[j], acc[i][j], 0, 0, 0);
        }
    };

    // prologue
    aload(0);
    bstage(0, 0);
    astore(0);                 // compiler inserts the Ra waitcnt here
    __syncthreads();           // drains DMA (B0) + lgkm

    for (int s = 0; s < KST3; ++s) {
        int buf = s & 1;
        if (s + 1 < KST3) {
            aload(s + 1);                      // issue early
            bstage(buf ^ 1, s + 1);            // DMA next B; covered by compute below
            compute(buf);
            astore(buf ^ 1);                   // Ra wait lands AFTER compute
        } else {
            compute(buf);
        }
        __syncthreads();                       // drains next-tile DMA + LDS writes
    }

    // epilogue: C/D layout col = lane&15, row = (lane>>4)*4 + r  [m89/m91]
    int orow = (lane >> 4) * 4, ocol = lane & 15;
    #pragma unroll
    for (int i = 0; i < 4; ++i)
        #pragma unroll
        for (int j = 0; j < 6; ++j)
            #pragma unroll
            for (int r = 0; r < 4; ++r)
                atomicAdd(&fused[(size_t)(m0 + wm*64 + i*16 + orow + r) * NH3
                                 + (wn*96 + j*16 + ocol)], acc[i][j][r]);
}

// ---------------- kernel E: h = relu(fused @ Wf1 + bf1), 4 rows/block ----------------
__global__ void mlp1(const float* __restrict__ fused, const float* __restrict__ Wf1,
                     const float* __restrict__ bf1, float* __restrict__ h) {
    int b = blockIdx.x * 4 + (threadIdx.x >> 7);
    int j = threadIdx.x & 127;
    float acc = bf1[j];
    const float* fr = fused + (size_t)b * NH3;
    #pragma unroll 4
    for (int i = 0; i < NH3; ++i) acc = fmaf(fr[i], Wf1[(size_t)i * HDIM + j], acc);
    h[(size_t)b * HDIM + j] = fmaxf(acc, 0.f);
}

// ---------------- kernel F: out = h @ Wf2 + bf2 ----------------
__global__ void mlp2(const float* __restrict__ h, const float* __restrict__ Wf2,
                     const float* __restrict__ bf2, float* __restrict__ out) {
    int idx = blockIdx.x * blockDim.x + threadIdx.x;
    if (idx >= BATCH * NCLS) return;
    int b = idx / NCLS, c = idx % NCLS;
    float acc = bf2[c];
    const float* hr = h + (size_t)b * HDIM;
    for (int i = 0; i < HDIM; ++i) acc = fmaf(hr[i], Wf2[(size_t)i * NCLS + c], acc);
    out[idx] = acc;
}

extern "C" void kernel_launch(void* const* d_in, const int* in_sizes, int n_in,
                              void* d_out, int out_size, void* d_ws, size_t ws_size,
                              hipStream_t stream) {
    const float* x   = (const float*)d_in[0];
    const float* We0 = (const float*)d_in[1];
    const float* be0 = (const float*)d_in[2];
    const float* We1 = (const float*)d_in[3];
    const float* be1 = (const float*)d_in[4];
    const float* We2 = (const float*)d_in[5];
    const float* be2 = (const float*)d_in[6];
    const float* Wf1 = (const float*)d_in[7];
    const float* bf1 = (const float*)d_in[8];
    const float* Wf2 = (const float*)d_in[9];
    const float* bf2 = (const float*)d_in[10];
    float* out = (float*)d_out;

    char* wsb = (char*)d_ws;
    size_t off = 0;
    unsigned short* Wp = (unsigned short*)(wsb + off); off += (size_t)NH3 * DDIM * sizeof(unsigned short); // 12.6 MB
    float* u     = (float*)(wsb + off); off += (size_t)2 * PERIOD * FH * sizeof(float);                    // 0.39 MB
    float* fused = (float*)(wsb + off); off += (size_t)BATCH * NH3 * sizeof(float);                        // 1.57 MB
    float* hbuf  = (float*)(wsb + off); off += (size_t)BATCH * HDIM * sizeof(float);                       // 0.52 MB

    init_phase<<<(BATCH * NH3 + 255) / 256, 256, 0, stream>>>(be0, be1, be2, We1, We2, fused, u);
    build_wp<<<dim3(8, L_LEN / NLB), 256, 0, stream>>>(We0, We2, u, Wp);
    gemm_big<<<8 * SPL3, 512, 0, stream>>>(x, Wp, fused);
    mlp1<<<BATCH / 4, 512, 0, stream>>>(fused, Wf1, bf1, hbuf);
    mlp2<<<(BATCH * NCLS + 255) / 256, 256, 0, stream>>>(hbuf, Wf2, bf2, out);
}

// Round 13
// 116.942 us; speedup vs baseline: 1.3012x; 1.3012x over previous
//
#include <hip/hip_runtime.h>

#define L_LEN  1024
#define FDIM   16
#define PERIOD 24
#define HDIM   128
#define BATCH  1024
#define DDIM   (L_LEN*FDIM)      // 16384
#define NH3    (3*HDIM)          // 384
#define THALF  12
#define NCLS   10
#define FH     (FDIM*HDIM)       // 2048
#define NLB    8                 // l-strip per build_wp block

typedef short bf16x8  __attribute__((ext_vector_type(8)));
typedef short bf16x16 __attribute__((ext_vector_type(16)));
typedef float f32x4   __attribute__((ext_vector_type(4)));
typedef unsigned int u32x4 __attribute__((ext_vector_type(4)));

__device__ __forceinline__ unsigned short f2bf(float f) {
    unsigned int u = __float_as_uint(f);
    u += 0x7FFFu + ((u >> 16) & 1u);           // RNE
    return (unsigned short)(u >> 16);
}
__device__ __forceinline__ float cinv(int p) { return (p < 16) ? (1.0f/43.0f) : (1.0f/42.0f); }

// ---------------- kernel B: per-phase column sums only (f32x4) ----------------
__global__ void phase_sums(const float* __restrict__ We1, const float* __restrict__ We2,
                           float* __restrict__ u) {
    int idx = blockIdx.x * blockDim.x + threadIdx.x;
    if (idx >= 2 * PERIOD * (FH / 4)) return;
    int w    = idx / (PERIOD * (FH / 4));
    int rem  = idx % (PERIOD * (FH / 4));
    int p    = rem / (FH / 4);
    int fh4  = rem % (FH / 4);
    const float* W = (w == 0) ? We1 : We2;
    f32x4 s = {0.f, 0.f, 0.f, 0.f};
    for (int l = p; l < L_LEN; l += PERIOD)
        s += *(const f32x4*)&W[(size_t)l * FH + fh4 * 4];
    *(f32x4*)&u[(size_t)w * PERIOD * FH + p * FH + fh4 * 4] = s;
}

// ---------------- kernel C: build W' (bf16) — register-window, spill-free ----------------
__launch_bounds__(256, 3)
__global__ void build_wp(const float* __restrict__ We0, const float* __restrict__ We2,
                         const float* __restrict__ u, unsigned short* __restrict__ Wp) {
    __shared__ unsigned short tile[3][NLB][16][18];   // 13.8 KB
    int f  = threadIdx.x >> 4;
    int hl = threadIdx.x & 15;
    int h  = blockIdx.x * 16 + hl;
    int l0 = blockIdx.y * NLB;
    int fh = f * HDIM + h;
    const float* u1 = u;
    const float* u2 = u + PERIOD * FH;

    float w0[NLB + 25], w2[NLB + 25];
    #pragma unroll
    for (int i = 0; i < NLB + 25; ++i) {
        int j = l0 - THALF + i;
        if (j >= 0 && j < L_LEN) {
            w0[i] = We0[(size_t)j * FH + fh];
            w2[i] = We2[(size_t)j * FH + fh];
        } else { w0[i] = 0.f; w2[i] = 0.f; }
    }

    float Sv1 = 0.f, Sv2 = 0.f;
    #pragma unroll
    for (int p = 0; p < PERIOD; ++p) {
        float ci = cinv(p);
        Sv1 += u1[p * FH + fh] * ci;
        Sv2 += u2[p * FH + fh] * ci;
    }

    float s0 = 0.f, s2 = 0.f;
    #pragma unroll
    for (int i = 0; i < 25; ++i) { s0 += w0[i]; s2 += w2[i]; }

    const float inv25 = 1.0f / 25.0f;
    #pragma unroll
    for (int r = 0; r < NLB; ++r) {
        int l = l0 + r;
        float out0 = s0 * inv25;
        float mav1, mav2;
        if (l >= THALF && l < L_LEN - THALF) {
            int pr = (l + THALF) % PERIOD;
            float cr = cinv(pr);
            mav1 = (Sv1 + u1[pr * FH + fh] * cr) * inv25;
            mav2 = (Sv2 + u2[pr * FH + fh] * cr) * inv25;
        } else {
            mav1 = 0.f; mav2 = 0.f;
            #pragma unroll
            for (int dl = -THALF; dl <= THALF; ++dl) {
                int j = l + dl;
                if (j >= 0 && j < L_LEN) {
                    int p = j % PERIOD;
                    float ci = cinv(p);
                    mav1 += u1[p * FH + fh] * ci;
                    mav2 += u2[p * FH + fh] * ci;
                }
            }
            mav1 *= inv25; mav2 *= inv25;
        }
        int   pl  = l % PERIOD;
        float cl  = cinv(pl);
        float v1l = u1[pl * FH + fh] * cl;
        float v2l = u2[pl * FH + fh] * cl;
        float out1 = v1l - mav1;
        float out2 = w2[r + THALF] - s2 * inv25 - v2l + mav2;

        tile[0][r][hl][f] = f2bf(out0);
        tile[1][r][hl][f] = f2bf(out1);
        tile[2][r][hl][f] = f2bf(out2);

        s0 += w0[r + 25] - w0[r];
        s2 += w2[r + 25] - w2[r];
    }
    __syncthreads();

    {
        int cid = threadIdx.x;
        #pragma unroll
        for (int pass = 0; pass < 2; ++pass, cid += 256) {
            if (cid < 3 * 16 * NLB) {
                int m  = cid / (16 * NLB);
                int rm = cid % (16 * NLB);
                int h2 = rm / NLB;
                int ll = rm % NLB;
                const unsigned int* src = (const unsigned int*)&tile[m][ll][h2][0];
                union { unsigned int d[8]; bf16x16 v; } cvt;
                #pragma unroll
                for (int i = 0; i < 8; ++i) cvt.d[i] = src[i];
                *(bf16x16*)&Wp[(size_t)(m * HDIM + blockIdx.x * 16 + h2) * DDIM
                               + (size_t)(l0 + ll) * FDIM] = cvt.v;
            }
        }
    }
}

// ---------------- kernel D: part[z] = x @ Wp^T slice — R6 champion + streaming stores ----------------
#define GBM 64
#define GBN 128
#define GBK 64
#define GSPLIT 16
#define GKSPL (DDIM / GSPLIT)    // 1024
#define GKST  (GKSPL / GBK)      // 16
#define LDA   72                 // A LDS stride: 144B ≡ 4 dwords mod 32 -> 2-way (free)
#define NWG   (16 * 3 * GSPLIT)  // 768 blocks, %8==0 (bijective XCD swizzle)

__launch_bounds__(256, 3)
__global__ void gemm2(const float* __restrict__ x, const unsigned short* __restrict__ Wp,
                      float* __restrict__ part) {
    __shared__ unsigned short As[2][GBM * LDA];   // 2 x 9.2 KB
    __shared__ unsigned short Bs[2][GBN * GBK];   // 2 x 16 KB, linear dest, swizzled content
    int bid = blockIdx.x;
    int swz = (bid & 7) * (NWG / 8) + (bid >> 3);
    int bz  = swz / 48;
    int rem = swz % 48;
    int by  = rem / 16;
    int bx  = rem % 16;
    int m0 = bx * GBM, n0 = by * GBN, k0 = bz * GKSPL;
    int tid = threadIdx.x, lane = tid & 63, wave = tid >> 6;
    int wm = wave >> 1, wn = wave & 1;

    int arow = tid >> 2, aseg = tid & 3;
    const float* ag = x + (size_t)(m0 + arow) * DDIM + k0 + aseg * 16;
    int brc  = lane >> 3;                       // row within 8-row chunk
    int bsg  = (lane & 7) ^ brc;                // T2 source-pre-swizzle

    f32x4 Ra[4], Rb[4];
    f32x4 acc[2][4] = {};

    auto aload = [&](f32x4* R, int s) {
        const float* a = ag + s * GBK;
        #pragma unroll
        for (int i = 0; i < 4; ++i) R[i] = *(const f32x4*)(a + 4 * i);
    };
    auto astore = [&](const f32x4* R, int buf) {
        unsigned int w[8];
        #pragma unroll
        for (int t = 0; t < 8; ++t) {
            float lo = R[t >> 1][(t & 1) * 2];
            float hi = R[t >> 1][(t & 1) * 2 + 1];
            asm("v_cvt_pk_bf16_f32 %0, %1, %2" : "=v"(w[t]) : "v"(lo), "v"(hi));
        }
        unsigned short* dst = &As[buf][arow * LDA + aseg * 16];
        u32x4 v0 = {w[0], w[1], w[2], w[3]};
        u32x4 v1 = {w[4], w[5], w[6], w[7]};
        *(u32x4*)dst       = v0;
        *(u32x4*)(dst + 8) = v1;
    };
    auto bstage = [&](int buf, int s) {
        #pragma unroll
        for (int q = 0; q < 4; ++q) {
            int c = wave * 4 + q;                  // 8-row chunk id (0..15)
            const unsigned short* g = Wp + (size_t)(n0 + c * 8 + brc) * DDIM
                                        + k0 + s * GBK + bsg * 8;
            __builtin_amdgcn_global_load_lds(
                (const __attribute__((address_space(1))) void*)g,
                (__attribute__((address_space(3))) void*)&Bs[buf][c * 512], 16, 0, 0);
        }
    };
    int frow = lane & 15, hi4 = lane >> 4;
    auto compute = [&](int buf) {
        #pragma unroll
        for (int ks = 0; ks < 2; ++ks) {
            bf16x8 av[2], bv[4];
            #pragma unroll
            for (int i = 0; i < 2; ++i)
                av[i] = *(const bf16x8*)&As[buf][(wm*32 + i*16 + frow) * LDA + ks*32 + hi4*8];
            #pragma unroll
            for (int j = 0; j < 4; ++j) {
                int rB = wn*64 + j*16 + frow;
                int sL = (ks*4 + hi4) ^ (frow & 7);    // un-swizzle on read
                bv[j] = *(const bf16x8*)&Bs[buf][rB * GBK + sL * 8];
            }
            #pragma unroll
            for (int i = 0; i < 2; ++i)
                #pragma unroll
                for (int j = 0; j < 4; ++j)
                    acc[i][j] = __builtin_amdgcn_mfma_f32_16x16x32_bf16(av[i], bv[j], acc[i][j], 0, 0, 0);
        }
    };

    // prologue (R6 champion): regs k0,k1; B0 DMA; A0 in LDS; barrier drains all
    aload(Ra, 0); aload(Rb, 1); bstage(0, 0); astore(Ra, 0);
    __syncthreads();

    for (int s2 = 0; s2 < GKST; s2 += 2) {
        {   int s = s2;                                  // even step, bufs 0
            if (s + 1 < GKST) bstage(1, s + 1);
            if (s + 2 < GKST) aload(Ra, s + 2);
            if (s + 1 < GKST) astore(Rb, 1);
            compute(0);
            __syncthreads();
        }
        {   int s = s2 + 1;                              // odd step, bufs 1
            if (s + 1 < GKST) bstage(0, s + 1);
            if (s + 2 < GKST) aload(Rb, s + 2);
            if (s + 1 < GKST) astore(Ra, 0);
            compute(1);
            __syncthreads();
        }
    }

    // epilogue: PLAIN streaming stores to this k-split's private slab (no atomics)
    float* pslab = part + (size_t)bz * (BATCH * NH3);
    int orow = (lane >> 4) * 4, ocol = lane & 15;   // C/D: col=lane&15, row=(lane>>4)*4+r
    #pragma unroll
    for (int i = 0; i < 2; ++i)
        #pragma unroll
        for (int j = 0; j < 4; ++j)
            #pragma unroll
            for (int r = 0; r < 4; ++r)
                pslab[(size_t)(m0 + wm*32 + i*16 + orow + r) * NH3
                      + (n0 + wn*64 + j*16 + ocol)] = acc[i][j][r];
}

// ---------------- kernel E: h = relu((Σ_z part[z] + be) @ Wf1 + bf1), 4 rows/block ----------------
__global__ void mlp1f(const float* __restrict__ part, const float* __restrict__ be0,
                      const float* __restrict__ be1, const float* __restrict__ be2,
                      const float* __restrict__ Wf1, const float* __restrict__ bf1,
                      float* __restrict__ h) {
    __shared__ float fr[4 * NH3];   // 6 KB
    int b0 = blockIdx.x * 4;
    for (int cid = threadIdx.x; cid < 4 * NH3; cid += 512) {
        int rr = cid / NH3, cc = cid % NH3;
        float v = (cc < HDIM) ? be0[cc] : (cc < 2*HDIM ? be1[cc - HDIM] : be2[cc - 2*HDIM]);
        #pragma unroll
        for (int z = 0; z < GSPLIT; ++z)
            v += part[(size_t)z * (BATCH * NH3) + (size_t)(b0 + rr) * NH3 + cc];
        fr[cid] = v;
    }
    __syncthreads();
    int row = threadIdx.x >> 7, j = threadIdx.x & 127;
    float acc = bf1[j];
    const float* f = &fr[row * NH3];
    #pragma unroll 4
    for (int i = 0; i < NH3; ++i) acc = fmaf(f[i], Wf1[(size_t)i * HDIM + j], acc);
    h[(size_t)(b0 + row) * HDIM + j] = fmaxf(acc, 0.f);
}

// ---------------- kernel F: out = h @ Wf2 + bf2 ----------------
__global__ void mlp2(const float* __restrict__ h, const float* __restrict__ Wf2,
                     const float* __restrict__ bf2, float* __restrict__ out) {
    int idx = blockIdx.x * blockDim.x + threadIdx.x;
    if (idx >= BATCH * NCLS) return;
    int b = idx / NCLS, c = idx % NCLS;
    float acc = bf2[c];
    const float* hr = h + (size_t)b * HDIM;
    for (int i = 0; i < HDIM; ++i) acc = fmaf(hr[i], Wf2[(size_t)i * NCLS + c], acc);
    out[idx] = acc;
}

extern "C" void kernel_launch(void* const* d_in, const int* in_sizes, int n_in,
                              void* d_out, int out_size, void* d_ws, size_t ws_size,
                              hipStream_t stream) {
    const float* x   = (const float*)d_in[0];
    const float* We0 = (const float*)d_in[1];
    const float* be0 = (const float*)d_in[2];
    const float* We1 = (const float*)d_in[3];
    const float* be1 = (const float*)d_in[4];
    const float* We2 = (const float*)d_in[5];
    const float* be2 = (const float*)d_in[6];
    const float* Wf1 = (const float*)d_in[7];
    const float* bf1 = (const float*)d_in[8];
    const float* Wf2 = (const float*)d_in[9];
    const float* bf2 = (const float*)d_in[10];
    float* out = (float*)d_out;

    char* wsb = (char*)d_ws;
    size_t off = 0;
    unsigned short* Wp = (unsigned short*)(wsb + off); off += (size_t)NH3 * DDIM * sizeof(unsigned short);   // 12.6 MB
    float* u    = (float*)(wsb + off); off += (size_t)2 * PERIOD * FH * sizeof(float);                       // 0.39 MB
    float* part = (float*)(wsb + off); off += (size_t)GSPLIT * BATCH * NH3 * sizeof(float);                  // 25.2 MB
    float* hbuf = (float*)(wsb + off); off += (size_t)BATCH * HDIM * sizeof(float);                          // 0.52 MB

    phase_sums<<<(2 * PERIOD * (FH / 4) + 255) / 256, 256, 0, stream>>>(We1, We2, u);
    build_wp<<<dim3(8, L_LEN / NLB), 256, 0, stream>>>(We0, We2, u, Wp);
    gemm2<<<NWG, 256, 0, stream>>>(x, Wp, part);
    mlp1f<<<BATCH / 4, 512, 0, stream>>>(part, be0, be1, be2, Wf1, bf1, hbuf);
    mlp2<<<(BATCH * NCLS + 255) / 256, 256, 0, stream>>>(hbuf, Wf2, bf2, out);
}

// Round 14
// 91.055 us; speedup vs baseline: 1.6712x; 1.2843x over previous
//
#include <hip/hip_runtime.h>

#define L_LEN  1024
#define FDIM   16
#define PERIOD 24
#define HDIM   128
#define BATCH  1024
#define DDIM   (L_LEN*FDIM)      // 16384
#define NH3    (3*HDIM)          // 384
#define THALF  12
#define NCLS   10
#define FH     (FDIM*HDIM)       // 2048
#define NLB    8                 // l-strip per build_wp block

typedef short bf16x8  __attribute__((ext_vector_type(8)));
typedef short bf16x16 __attribute__((ext_vector_type(16)));
typedef float f32x4   __attribute__((ext_vector_type(4)));
typedef unsigned int u32x4 __attribute__((ext_vector_type(4)));

__device__ __forceinline__ unsigned short f2bf(float f) {
    unsigned int u = __float_as_uint(f);
    u += 0x7FFFu + ((u >> 16) & 1u);           // RNE
    return (unsigned short)(u >> 16);
}
__device__ __forceinline__ float cinv(int p) { return (p < 16) ? (1.0f/43.0f) : (1.0f/42.0f); }

// ---------------- kernel B: per-phase column sums only (f32x4) ----------------
__global__ void phase_sums(const float* __restrict__ We1, const float* __restrict__ We2,
                           float* __restrict__ u) {
    int idx = blockIdx.x * blockDim.x + threadIdx.x;
    if (idx >= 2 * PERIOD * (FH / 4)) return;
    int w    = idx / (PERIOD * (FH / 4));
    int rem  = idx % (PERIOD * (FH / 4));
    int p    = rem / (FH / 4);
    int fh4  = rem % (FH / 4);
    const float* W = (w == 0) ? We1 : We2;
    f32x4 s = {0.f, 0.f, 0.f, 0.f};
    for (int l = p; l < L_LEN; l += PERIOD)
        s += *(const f32x4*)&W[(size_t)l * FH + fh4 * 4];
    *(f32x4*)&u[(size_t)w * PERIOD * FH + p * FH + fh4 * 4] = s;
}

// ---------------- kernel C: build W' (bf16) — register-window, spill-free ----------------
__launch_bounds__(256, 3)
__global__ void build_wp(const float* __restrict__ We0, const float* __restrict__ We2,
                         const float* __restrict__ u, unsigned short* __restrict__ Wp) {
    __shared__ unsigned short tile[3][NLB][16][18];   // 13.8 KB
    int f  = threadIdx.x >> 4;
    int hl = threadIdx.x & 15;
    int h  = blockIdx.x * 16 + hl;
    int l0 = blockIdx.y * NLB;
    int fh = f * HDIM + h;
    const float* u1 = u;
    const float* u2 = u + PERIOD * FH;

    float w0[NLB + 25], w2[NLB + 25];
    #pragma unroll
    for (int i = 0; i < NLB + 25; ++i) {
        int j = l0 - THALF + i;
        if (j >= 0 && j < L_LEN) {
            w0[i] = We0[(size_t)j * FH + fh];
            w2[i] = We2[(size_t)j * FH + fh];
        } else { w0[i] = 0.f; w2[i] = 0.f; }
    }

    float Sv1 = 0.f, Sv2 = 0.f;
    #pragma unroll
    for (int p = 0; p < PERIOD; ++p) {
        float ci = cinv(p);
        Sv1 += u1[p * FH + fh] * ci;
        Sv2 += u2[p * FH + fh] * ci;
    }

    float s0 = 0.f, s2 = 0.f;
    #pragma unroll
    for (int i = 0; i < 25; ++i) { s0 += w0[i]; s2 += w2[i]; }

    const float inv25 = 1.0f / 25.0f;
    #pragma unroll
    for (int r = 0; r < NLB; ++r) {
        int l = l0 + r;
        float out0 = s0 * inv25;
        float mav1, mav2;
        if (l >= THALF && l < L_LEN - THALF) {
            int pr = (l + THALF) % PERIOD;
            float cr = cinv(pr);
            mav1 = (Sv1 + u1[pr * FH + fh] * cr) * inv25;
            mav2 = (Sv2 + u2[pr * FH + fh] * cr) * inv25;
        } else {
            mav1 = 0.f; mav2 = 0.f;
            #pragma unroll
            for (int dl = -THALF; dl <= THALF; ++dl) {
                int j = l + dl;
                if (j >= 0 && j < L_LEN) {
                    int p = j % PERIOD;
                    float ci = cinv(p);
                    mav1 += u1[p * FH + fh] * ci;
                    mav2 += u2[p * FH + fh] * ci;
                }
            }
            mav1 *= inv25; mav2 *= inv25;
        }
        int   pl  = l % PERIOD;
        float cl  = cinv(pl);
        float v1l = u1[pl * FH + fh] * cl;
        float v2l = u2[pl * FH + fh] * cl;
        float out1 = v1l - mav1;
        float out2 = w2[r + THALF] - s2 * inv25 - v2l + mav2;

        tile[0][r][hl][f] = f2bf(out0);
        tile[1][r][hl][f] = f2bf(out1);
        tile[2][r][hl][f] = f2bf(out2);

        s0 += w0[r + 25] - w0[r];
        s2 += w2[r + 25] - w2[r];
    }
    __syncthreads();

    {
        int cid = threadIdx.x;
        #pragma unroll
        for (int pass = 0; pass < 2; ++pass, cid += 256) {
            if (cid < 3 * 16 * NLB) {
                int m  = cid / (16 * NLB);
                int rm = cid % (16 * NLB);
                int h2 = rm / NLB;
                int ll = rm % NLB;
                const unsigned int* src = (const unsigned int*)&tile[m][ll][h2][0];
                union { unsigned int d[8]; bf16x16 v; } cvt;
                #pragma unroll
                for (int i = 0; i < 8; ++i) cvt.d[i] = src[i];
                *(bf16x16*)&Wp[(size_t)(m * HDIM + blockIdx.x * 16 + h2) * DDIM
                               + (size_t)(l0 + ll) * FDIM] = cvt.v;
            }
        }
    }
}

// ---------------- kernel D: part[z] = x @ Wp^T slice — R6 structure + streaming stores ----------------
#define GBM 64
#define GBN 128
#define GBK 64
#define GSPLIT 16
#define GKSPL (DDIM / GSPLIT)    // 1024
#define GKST  (GKSPL / GBK)      // 16
#define LDA   72                 // A LDS stride: 144B ≡ 4 dwords mod 32 -> 2-way (free)
#define NWG   (16 * 3 * GSPLIT)  // 768 blocks, %8==0 (bijective XCD swizzle)

__launch_bounds__(256, 3)
__global__ void gemm2(const float* __restrict__ x, const unsigned short* __restrict__ Wp,
                      float* __restrict__ part) {
    __shared__ unsigned short As[2][GBM * LDA];   // 2 x 9.2 KB
    __shared__ unsigned short Bs[2][GBN * GBK];   // 2 x 16 KB, linear dest, swizzled content
    int bid = blockIdx.x;
    int swz = (bid & 7) * (NWG / 8) + (bid >> 3);
    int bz  = swz / 48;
    int rem = swz % 48;
    int by  = rem / 16;
    int bx  = rem % 16;
    int m0 = bx * GBM, n0 = by * GBN, k0 = bz * GKSPL;
    int tid = threadIdx.x, lane = tid & 63, wave = tid >> 6;
    int wm = wave >> 1, wn = wave & 1;

    int arow = tid >> 2, aseg = tid & 3;
    const float* ag = x + (size_t)(m0 + arow) * DDIM + k0 + aseg * 16;
    int brc  = lane >> 3;                       // row within 8-row chunk
    int bsg  = (lane & 7) ^ brc;                // T2 source-pre-swizzle

    f32x4 Ra[4], Rb[4];
    f32x4 acc[2][4] = {};

    auto aload = [&](f32x4* R, int s) {
        const float* a = ag + s * GBK;
        #pragma unroll
        for (int i = 0; i < 4; ++i) R[i] = *(const f32x4*)(a + 4 * i);
    };
    auto astore = [&](const f32x4* R, int buf) {
        unsigned int w[8];
        #pragma unroll
        for (int t = 0; t < 8; ++t) {
            float lo = R[t >> 1][(t & 1) * 2];
            float hi = R[t >> 1][(t & 1) * 2 + 1];
            asm("v_cvt_pk_bf16_f32 %0, %1, %2" : "=v"(w[t]) : "v"(lo), "v"(hi));
        }
        unsigned short* dst = &As[buf][arow * LDA + aseg * 16];
        u32x4 v0 = {w[0], w[1], w[2], w[3]};
        u32x4 v1 = {w[4], w[5], w[6], w[7]};
        *(u32x4*)dst       = v0;
        *(u32x4*)(dst + 8) = v1;
    };
    auto bstage = [&](int buf, int s) {
        #pragma unroll
        for (int q = 0; q < 4; ++q) {
            int c = wave * 4 + q;                  // 8-row chunk id (0..15)
            const unsigned short* g = Wp + (size_t)(n0 + c * 8 + brc) * DDIM
                                        + k0 + s * GBK + bsg * 8;
            __builtin_amdgcn_global_load_lds(
                (const __attribute__((address_space(1))) void*)g,
                (__attribute__((address_space(3))) void*)&Bs[buf][c * 512], 16, 0, 0);
        }
    };
    int frow = lane & 15, hi4 = lane >> 4;
    auto compute = [&](int buf) {
        #pragma unroll
        for (int ks = 0; ks < 2; ++ks) {
            bf16x8 av[2], bv[4];
            #pragma unroll
            for (int i = 0; i < 2; ++i)
                av[i] = *(const bf16x8*)&As[buf][(wm*32 + i*16 + frow) * LDA + ks*32 + hi4*8];
            #pragma unroll
            for (int j = 0; j < 4; ++j) {
                int rB = wn*64 + j*16 + frow;
                int sL = (ks*4 + hi4) ^ (frow & 7);    // un-swizzle on read
                bv[j] = *(const bf16x8*)&Bs[buf][rB * GBK + sL * 8];
            }
            #pragma unroll
            for (int i = 0; i < 2; ++i)
                #pragma unroll
                for (int j = 0; j < 4; ++j)
                    acc[i][j] = __builtin_amdgcn_mfma_f32_16x16x32_bf16(av[i], bv[j], acc[i][j], 0, 0, 0);
        }
    };

    // prologue: regs k0,k1; B0 DMA; A0 in LDS; barrier drains all
    aload(Ra, 0); aload(Rb, 1); bstage(0, 0); astore(Ra, 0);
    __syncthreads();

    for (int s2 = 0; s2 < GKST; s2 += 2) {
        {   int s = s2;                                  // even step, bufs 0
            if (s + 1 < GKST) bstage(1, s + 1);
            if (s + 2 < GKST) aload(Ra, s + 2);
            if (s + 1 < GKST) astore(Rb, 1);
            compute(0);
            __syncthreads();
        }
        {   int s = s2 + 1;                              // odd step, bufs 1
            if (s + 1 < GKST) bstage(0, s + 1);
            if (s + 2 < GKST) aload(Rb, s + 2);
            if (s + 1 < GKST) astore(Ra, 0);
            compute(1);
            __syncthreads();
        }
    }

    // epilogue: PLAIN streaming stores to this k-split's private slab (no atomics)
    float* pslab = part + (size_t)bz * (BATCH * NH3);
    int orow = (lane >> 4) * 4, ocol = lane & 15;   // C/D: col=lane&15, row=(lane>>4)*4+r
    #pragma unroll
    for (int i = 0; i < 2; ++i)
        #pragma unroll
        for (int j = 0; j < 4; ++j)
            #pragma unroll
            for (int r = 0; r < 4; ++r)
                pslab[(size_t)(m0 + wm*32 + i*16 + orow + r) * NH3
                      + (n0 + wn*64 + j*16 + ocol)] = acc[i][j][r];
}

// ---------------- kernel E: fused MLP tail — one block per batch row ----------------
// out[b] = (relu((Σ_z part[z][b] + be) @ Wf1 + bf1)) @ Wf2 + bf2
// 512 thr: (j = t&127, c = t>>7); dot split 4x across c AND 4 partial accs -> chain 24.
__launch_bounds__(512, 4)
__global__ void mlp_fused(const float* __restrict__ part, const float* __restrict__ be0,
                          const float* __restrict__ be1, const float* __restrict__ be2,
                          const float* __restrict__ Wf1, const float* __restrict__ bf1,
                          const float* __restrict__ Wf2, const float* __restrict__ bf2,
                          float* __restrict__ out) {
    __shared__ float fr[NH3];        // 1.5 KB
    __shared__ float hp[4][HDIM];    // 2 KB
    __shared__ float hs[HDIM];       // 0.5 KB
    int b = blockIdx.x, tid = threadIdx.x;

    if (tid < NH3) {
        float v = (tid < HDIM) ? be0[tid]
                : (tid < 2*HDIM ? be1[tid - HDIM] : be2[tid - 2*HDIM]);
        #pragma unroll
        for (int z = 0; z < GSPLIT; ++z)             // 16 independent loads
            v += part[(size_t)z * (BATCH * NH3) + (size_t)b * NH3 + tid];
        fr[tid] = v;
    }
    __syncthreads();

    int j = tid & 127, c = tid >> 7;                 // c-chunk of 96 i's
    int i0 = c * 96;
    float p0 = 0.f, p1 = 0.f, p2 = 0.f, p3 = 0.f;
    #pragma unroll
    for (int k = 0; k < 24; ++k) {                   // 4 independent chains of 24
        p0 = fmaf(fr[i0 + k],      Wf1[(size_t)(i0 + k)      * HDIM + j], p0);
        p1 = fmaf(fr[i0 + 24 + k], Wf1[(size_t)(i0 + 24 + k) * HDIM + j], p1);
        p2 = fmaf(fr[i0 + 48 + k], Wf1[(size_t)(i0 + 48 + k) * HDIM + j], p2);
        p3 = fmaf(fr[i0 + 72 + k], Wf1[(size_t)(i0 + 72 + k) * HDIM + j], p3);
    }
    hp[c][j] = (p0 + p1) + (p2 + p3);
    __syncthreads();

    if (tid < HDIM) {
        float v = bf1[tid] + ((hp[0][tid] + hp[1][tid]) + (hp[2][tid] + hp[3][tid]));
        hs[tid] = fmaxf(v, 0.f);
    }
    __syncthreads();

    int lane = tid & 63, wave = tid >> 6;
    for (int cc = wave; cc < NCLS; cc += 8) {        // waves 0..7 -> classes; 0,1 take 8,9
        float pp = hs[lane] * Wf2[(size_t)lane * NCLS + cc];
        pp = fmaf(hs[lane + 64], Wf2[(size_t)(lane + 64) * NCLS + cc], pp);
        #pragma unroll
        for (int off = 32; off; off >>= 1) pp += __shfl_down(pp, off);
        if (lane == 0) out[(size_t)b * NCLS + cc] = pp + bf2[cc];
    }
}

extern "C" void kernel_launch(void* const* d_in, const int* in_sizes, int n_in,
                              void* d_out, int out_size, void* d_ws, size_t ws_size,
                              hipStream_t stream) {
    const float* x   = (const float*)d_in[0];
    const float* We0 = (const float*)d_in[1];
    const float* be0 = (const float*)d_in[2];
    const float* We1 = (const float*)d_in[3];
    const float* be1 = (const float*)d_in[4];
    const float* We2 = (const float*)d_in[5];
    const float* be2 = (const float*)d_in[6];
    const float* Wf1 = (const float*)d_in[7];
    const float* bf1 = (const float*)d_in[8];
    const float* Wf2 = (const float*)d_in[9];
    const float* bf2 = (const float*)d_in[10];
    float* out = (float*)d_out;

    char* wsb = (char*)d_ws;
    size_t off = 0;
    unsigned short* Wp = (unsigned short*)(wsb + off); off += (size_t)NH3 * DDIM * sizeof(unsigned short);   // 12.6 MB
    float* u    = (float*)(wsb + off); off += (size_t)2 * PERIOD * FH * sizeof(float);                       // 0.39 MB
    float* part = (float*)(wsb + off); off += (size_t)GSPLIT * BATCH * NH3 * sizeof(float);                  // 25.2 MB

    phase_sums<<<(2 * PERIOD * (FH / 4) + 255) / 256, 256, 0, stream>>>(We1, We2, u);
    build_wp<<<dim3(8, L_LEN / NLB), 256, 0, stream>>>(We0, We2, u, Wp);
    gemm2<<<NWG, 256, 0, stream>>>(x, Wp, part);
    mlp_fused<<<BATCH, 512, 0, stream>>>(part, be0, be1, be2, Wf1, bf1, Wf2, bf2, out);
}